// Round 12
// baseline (284.111 us; speedup 1.0000x reference)
//
#include <hip/hip_runtime.h>

#define N_NODES 50000
#define N_EDGES 1600000
#define N_CAND  131072
#define D 128
#define ROWS 50176   // padded row count
#define NB 196       // coarse buckets (dst>>8)
#define BCAP 10240   // fixed per-bucket capacity (E[cnt]=8192, sigma~90)
#define LSTR 132     // LDS row stride (bf16 elems)
#define ZROW 50000   // zeroed row: /dev/null target for padded gather slots

typedef __attribute__((ext_vector_type(8))) short short8;
typedef __attribute__((ext_vector_type(4))) float f32x4;
typedef __attribute__((ext_vector_type(2))) float float2v;

__device__ inline short f2bf(float f) {
  unsigned u = __builtin_bit_cast(unsigned, f);
  u = (u + 0x7FFFu + ((u >> 16) & 1u)) >> 16;
  return (short)u;
}
__device__ inline float bfu(unsigned short h) { return __builtin_bit_cast(float, (unsigned)h << 16); }

// pack 4 f32 -> 4 fp8 e4m3 (one u32) via HW cvt
__device__ inline unsigned pk_fp8x4(float a, float b, float c, float d) {
  unsigned lo = 0, hi = 0;
  asm("v_cvt_pk_fp8_f32 %0, %1, %2" : "+v"(lo) : "v"(a), "v"(b));
  asm("v_cvt_pk_fp8_f32 %0, %1, %2" : "+v"(hi) : "v"(c), "v"(d));
  return (lo & 0xFFFFu) | (hi << 16);
}

// LDS staging swizzle: spreads the 16 (kk,qq) slots of one row across 8 bank-quads
__device__ inline int swz(int b) { return b ^ (((b >> 8) & 7) << 4); }

// ---------------- prep + pass1 merged (x written row-major FP8; block 3580
// zeroes the ZROW rows, replacing two hipMemsetAsync dispatches) ----------------

__global__ __launch_bounds__(256) void prep_pass1(const float* __restrict__ gw1,
                                                  const float* __restrict__ gw2,
                                                  const float* __restrict__ pw1,
                                                  short* __restrict__ Wf,
                                                  const float* __restrict__ x,
                                                  unsigned char* __restrict__ y8,
                                                  unsigned char* __restrict__ y8b,
                                                  const int* __restrict__ src,
                                                  const int* __restrict__ dst,
                                                  int* __restrict__ bucket_cnt,
                                                  int* __restrict__ pairs) {
  int b = blockIdx.x;
  int t = threadIdx.x;
  if (b == 3580) {
    if (t < 32) {
      *(unsigned*)&y8[(size_t)ZROW * 128 + t * 4] = 0u;
      *(unsigned*)&y8b[(size_t)ZROW * 128 + t * 4] = 0u;
    }
    return;
  }
  if (b < 64) {
    int tid = b * 256 + t;  // 0..16383
    int img = tid >> 11, idx = tid & 2047;
    const float* W;
    if (img < 3) W = gw1 + img * 16384;
    else if (img < 6) W = gw2 + (img - 3) * 16384;
    else W = pw1 + (256 + (img - 6) * 128) * 128;
    int n = idx & 127, k8 = idx >> 7;
    short8 s;
#pragma unroll
    for (int j = 0; j < 8; ++j) s[j] = f2bf(W[(k8 * 8 + j) * 128 + n]);
    int kk = k8 >> 2, q = k8 & 3, nt = n >> 4, ln = (n & 15) | (q << 4);
    *(short8*)&Wf[img * 16384 + ((nt * 4 + kk) * 64 + ln) * 8] = s;
  } else if (b < 3189) {
    int tid = (b - 64) * 256 + t;       // 0..799999 ; 8 floats each
    size_t base = (size_t)tid * 8;
    float4 v0 = *(const float4*)&x[base];
    float4 v1 = *(const float4*)&x[base + 4];
    uint2 r;
    r.x = pk_fp8x4(v0.x, v0.y, v0.z, v0.w);
    r.y = pk_fp8x4(v1.x, v1.y, v1.z, v1.w);
    *(uint2*)&y8[base] = r;             // row-major fp8: node*128 + c8*8
  } else {
    __shared__ int lcnt[NB];
    __shared__ int loff[NB];
    __shared__ int gbase[NB];
    __shared__ int scanbuf[256];
    __shared__ int stage[4096];
    int e0 = (b - 3189) * 4096;
    for (int i = t; i < NB; i += 256) lcnt[i] = 0;
    __syncthreads();
    int d[16], s[16], r[16];
#pragma unroll
    for (int i = 0; i < 16; ++i) {
      int e = e0 + i * 256 + t;
      if (e < N_EDGES) {
        d[i] = dst[e]; s[i] = src[e];
        r[i] = atomicAdd(&lcnt[d[i] >> 8], 1);
      } else d[i] = -1;
    }
    __syncthreads();
    {
      int v = (t < NB) ? lcnt[t] : 0;
      scanbuf[t] = v;
      __syncthreads();
      for (int off = 1; off < 256; off <<= 1) {
        int add = (t >= off) ? scanbuf[t - off] : 0;
        __syncthreads();
        scanbuf[t] += add;
        __syncthreads();
      }
      if (t < NB) {
        loff[t] = scanbuf[t] - v;
        gbase[t] = v ? atomicAdd(&bucket_cnt[t], v) : 0;
      }
    }
    __syncthreads();
#pragma unroll
    for (int i = 0; i < 16; ++i) {
      if (d[i] >= 0) {
        int bb = d[i] >> 8;
        stage[loff[bb] + r[i]] = (s[i] << 8) | (d[i] & 255);
      }
    }
    __syncthreads();
    int w = t >> 6, lane = t & 63;
    for (int bb = w; bb < NB; bb += 4) {
      int c = lcnt[bb], lo = loff[bb], gb = bb * BCAP + gbase[bb];
      for (int k = lane; k < c; k += 64) pairs[gb + k] = stage[lo + k];
    }
  }
}

// ---------------- pass2: within-bucket counting sort (unchanged) ----------------

__global__ __launch_bounds__(512) void build_pass2(const int* __restrict__ pairs,
                                                   const int* __restrict__ bucket_cnt,
                                                   int2* __restrict__ rowBE,
                                                   int* __restrict__ csr) {
  __shared__ int cnt_s[256];
  __shared__ int buf[256];
  __shared__ int ssrc[BCAP];
  int t = threadIdx.x;
  int b = blockIdx.x;
  int cnt = bucket_cnt[b];
  int gbase = b * BCAP;
  const int* pp = pairs + gbase;
  if (t < 256) cnt_s[t] = 0;
  __syncthreads();
  for (int i = t; i < cnt; i += 512) atomicAdd(&cnt_s[pp[i] & 255], 1);
  __syncthreads();
  int v = 0;
  if (t < 256) { v = cnt_s[t]; buf[t] = v; }
  __syncthreads();
  for (int off = 1; off < 256; off <<= 1) {
    int add = (t >= off && t < 256) ? buf[t - off] : 0;
    __syncthreads();
    if (t < 256) buf[t] += add;
    __syncthreads();
  }
  if (t < 256) {
    int excl = buf[t] - v;
    int node = (b << 8) + t;
    if (node < N_NODES) rowBE[node] = make_int2(gbase + excl, gbase + excl + v);
    cnt_s[t] = excl;
  }
  __syncthreads();
  for (int i = t; i < cnt; i += 512) {
    int p = pp[i];
    int pos = atomicAdd(&cnt_s[p & 255], 1);
    ssrc[pos] = p >> 8;
  }
  __syncthreads();
  for (int i = t; i < cnt; i += 512) csr[gbase + i] = ssrc[i];
}

// ---------------- fused GIN layer v12: fp8 gather, 4 edges per 64-lane dwordx2
// load (quarter-wave = one full 128B row), ds_bpermute idx distribution,
// up-front latency-chain prefetch; tests per-instruction vs per-line wall. ----------

#if __has_builtin(__builtin_amdgcn_cvt_pk_f32_fp8)
#define CVTPK(u_, hi_) __builtin_amdgcn_cvt_pk_f32_fp8((int)(u_), (hi_))
#else
__device__ inline float2v cvtpk_asm(unsigned u, bool hi) {
  float2v r; unsigned s = hi ? (u >> 16) : u;
  asm("v_cvt_pk_f32_fp8 %0, %1" : "=v"(r) : "v"(s));
  return r;
}
#define CVTPK(u_, hi_) cvtpk_asm((u_), (hi_))
#endif

#define FADD4(v_) { a01 += CVTPK((v_).x, false); a23 += CVTPK((v_).x, true);  \
                    a45 += CVTPK((v_).y, false); a67 += CVTPK((v_).y, true); }

#define LADDER4(sidx_v, cnt_v) {                                                    \
    int ng_ = ((cnt_v) + 3) >> 2;                                                   \
    int ii_ = 0;                                                                    \
    for (; ii_ + 16 <= ng_; ii_ += 16) {                                            \
      uint2 v_[16];                                                                 \
      _Pragma("unroll")                                                             \
      for (int j_ = 0; j_ < 16; ++j_) {                                             \
        int row_ = __builtin_amdgcn_ds_bpermute(vb + (ii_ + j_) * 16, (sidx_v));    \
        v_[j_] = *(const uint2*)(xb + ((size_t)(unsigned)row_ << 7) + colb);        \
      }                                                                             \
      _Pragma("unroll")                                                             \
      for (int j_ = 0; j_ < 16; ++j_) FADD4(v_[j_]);                                \
    }                                                                               \
    for (; ii_ + 8 <= ng_; ii_ += 8) {                                              \
      uint2 v_[8];                                                                  \
      _Pragma("unroll")                                                             \
      for (int j_ = 0; j_ < 8; ++j_) {                                              \
        int row_ = __builtin_amdgcn_ds_bpermute(vb + (ii_ + j_) * 16, (sidx_v));    \
        v_[j_] = *(const uint2*)(xb + ((size_t)(unsigned)row_ << 7) + colb);        \
      }                                                                             \
      _Pragma("unroll")                                                             \
      for (int j_ = 0; j_ < 8; ++j_) FADD4(v_[j_]);                                 \
    }                                                                               \
    for (; ii_ + 4 <= ng_; ii_ += 4) {                                              \
      uint2 v_[4];                                                                  \
      _Pragma("unroll")                                                             \
      for (int j_ = 0; j_ < 4; ++j_) {                                              \
        int row_ = __builtin_amdgcn_ds_bpermute(vb + (ii_ + j_) * 16, (sidx_v));    \
        v_[j_] = *(const uint2*)(xb + ((size_t)(unsigned)row_ << 7) + colb);        \
      }                                                                             \
      _Pragma("unroll")                                                             \
      for (int j_ = 0; j_ < 4; ++j_) FADD4(v_[j_]);                                 \
    }                                                                               \
    for (; ii_ < ng_; ++ii_) {                                                      \
      int row_ = __builtin_amdgcn_ds_bpermute(vb + ii_ * 16, (sidx_v));             \
      uint2 v_ = *(const uint2*)(xb + ((size_t)(unsigned)row_ << 7) + colb);        \
      FADD4(v_);                                                                    \
    }                                                                               \
  }

__global__ __launch_bounds__(256) void gin_layer(const unsigned char* __restrict__ xf8,
                                                 const int2* __restrict__ rowBE,
                                                 const int* __restrict__ csr,
                                                 const short* __restrict__ B1f,
                                                 const float* __restrict__ b1,
                                                 const short* __restrict__ B2f,
                                                 const float* __restrict__ b2,
                                                 unsigned char* __restrict__ xf8out,
                                                 unsigned short* __restrict__ xbfout) {
  __shared__ short hbuf[16 * LSTR];   // 4224 B
  int t = threadIdx.x;
  int w = t >> 6, lane = t & 63;
  int vb = (lane & 48) >> 2;          // quadrant*4: bpermute byte-addr base
  int colb = (lane & 15) << 3;        // byte column within 128B fp8 row (8B each)
  int node0 = blockIdx.x * 16;        // grid 3125: exact cover of 50000
  const char* xb = (const char*)xf8;

  // ---- prefetch ALL per-node latency chains up front (independent batches) ----
  int2 be_[4];
#pragma unroll
  for (int i = 0; i < 4; ++i) be_[i] = rowBE[node0 + w * 4 + i];
  int sidx_[4];
#pragma unroll
  for (int i = 0; i < 4; ++i)
    sidx_[i] = (be_[i].x + lane < be_[i].y) ? csr[be_[i].x + lane] : ZROW;
  uint2 sv_[4];
#pragma unroll
  for (int i = 0; i < 4; ++i)
    sv_[i] = *(const uint2*)(xb + ((size_t)(node0 + w * 4 + i) << 7) + colb);

#pragma unroll
  for (int i = 0; i < 4; ++i) {
    int node = node0 + w * 4 + i;
    int beg = be_[i].x, end = be_[i].y;
    float2v a01 = {0.f, 0.f}, a23 = {0.f, 0.f}, a45 = {0.f, 0.f}, a67 = {0.f, 0.f};

    {
      int cnt0 = min(64, end - beg);
      LADDER4(sidx_[i], cnt0);
    }
#pragma unroll 1
    for (int e = beg + 64; e < end; e += 64) {   // rare: degree > 64
      int cnt = min(64, end - e);
      int sidx = (e + lane < end) ? csr[e + lane] : ZROW;
      LADDER4(sidx, cnt);
    }

    // reduce the 4 quadrant partials (each lane holds 8 dims)
    a01[0] += __shfl_xor(a01[0], 16, 64); a01[0] += __shfl_xor(a01[0], 32, 64);
    a01[1] += __shfl_xor(a01[1], 16, 64); a01[1] += __shfl_xor(a01[1], 32, 64);
    a23[0] += __shfl_xor(a23[0], 16, 64); a23[0] += __shfl_xor(a23[0], 32, 64);
    a23[1] += __shfl_xor(a23[1], 16, 64); a23[1] += __shfl_xor(a23[1], 32, 64);
    a45[0] += __shfl_xor(a45[0], 16, 64); a45[0] += __shfl_xor(a45[0], 32, 64);
    a45[1] += __shfl_xor(a45[1], 16, 64); a45[1] += __shfl_xor(a45[1], 32, 64);
    a67[0] += __shfl_xor(a67[0], 16, 64); a67[0] += __shfl_xor(a67[0], 32, 64);
    a67[1] += __shfl_xor(a67[1], 16, 64); a67[1] += __shfl_xor(a67[1], 32, 64);

    if (lane < 16) {
      // add own row (h = x + agg); lane m holds dims m*8..m*8+7
      uint2 svv = sv_[i];
      FADD4(svv);
      unsigned r0 = (unsigned)(unsigned short)f2bf(a01[0]) | ((unsigned)(unsigned short)f2bf(a01[1]) << 16);
      unsigned r1 = (unsigned)(unsigned short)f2bf(a23[0]) | ((unsigned)(unsigned short)f2bf(a23[1]) << 16);
      unsigned r2 = (unsigned)(unsigned short)f2bf(a45[0]) | ((unsigned)(unsigned short)f2bf(a45[1]) << 16);
      unsigned r3 = (unsigned)(unsigned short)f2bf(a67[0]) | ((unsigned)(unsigned short)f2bf(a67[1]) << 16);
      int row = w * 4 + i;
      uint2 lo; lo.x = r0; lo.y = r1;
      uint2 hi; hi.x = r2; hi.y = r3;
      *(uint2*)&hbuf[row * LSTR + lane * 8] = lo;        // 8B-aligned (264%8==0)
      *(uint2*)&hbuf[row * LSTR + lane * 8 + 4] = hi;
    }
  }
  __syncthreads();

  int q = lane >> 4, m = lane & 15;
  short8 a0f[4];
#pragma unroll
  for (int kk = 0; kk < 4; ++kk)
    a0f[kk] = *(short8*)&hbuf[m * LSTR + kk * 32 + q * 8];
  __syncthreads();

  f32x4 acc[2] = {};
#pragma unroll
  for (int kk = 0; kk < 4; ++kk)
#pragma unroll
    for (int j = 0; j < 2; ++j) {
      int nt = w * 2 + j;
      short8 bf = *(const short8*)&B1f[((nt * 4 + kk) * 64 + lane) * 8];
      acc[j] = __builtin_amdgcn_mfma_f32_16x16x32_bf16(a0f[kk], bf, acc[j], 0, 0, 0);
    }
#pragma unroll
  for (int j = 0; j < 2; ++j) {
    int nt = w * 2 + j;
    float bv = b1[nt * 16 + m];
#pragma unroll
    for (int r = 0; r < 4; ++r)
      hbuf[(q * 4 + r) * LSTR + nt * 16 + m] = f2bf(fmaxf(acc[j][r] + bv, 0.f));
  }
  __syncthreads();

  short8 a1f[4];
#pragma unroll
  for (int kk = 0; kk < 4; ++kk)
    a1f[kk] = *(short8*)&hbuf[m * LSTR + kk * 32 + q * 8];
  __syncthreads();

  f32x4 acc2v[2] = {};
#pragma unroll
  for (int kk = 0; kk < 4; ++kk)
#pragma unroll
    for (int j = 0; j < 2; ++j) {
      int nt = w * 2 + j;
      short8 bf = *(const short8*)&B2f[((nt * 4 + kk) * 64 + lane) * 8];
      acc2v[j] = __builtin_amdgcn_mfma_f32_16x16x32_bf16(a1f[kk], bf, acc2v[j], 0, 0, 0);
    }
#pragma unroll
  for (int j = 0; j < 2; ++j) {
    int nt = w * 2 + j;
    float bv = b2[nt * 16 + m];
#pragma unroll
    for (int r = 0; r < 4; ++r)
      hbuf[(q * 4 + r) * LSTR + nt * 16 + m] = f2bf(acc2v[j][r] + bv);
  }
  __syncthreads();

  {
    int row = t >> 4, c8 = t & 15;
    short8 vv = *(short8*)&hbuf[row * LSTR + c8 * 8];
    int node = node0 + row;
    if (xf8out) {
      float f0 = bfu((unsigned short)vv[0]), f1 = bfu((unsigned short)vv[1]);
      float f2 = bfu((unsigned short)vv[2]), f3 = bfu((unsigned short)vv[3]);
      float f4 = bfu((unsigned short)vv[4]), f5 = bfu((unsigned short)vv[5]);
      float f6 = bfu((unsigned short)vv[6]), f7 = bfu((unsigned short)vv[7]);
      uint2 r;
      r.x = pk_fp8x4(f0, f1, f2, f3);
      r.y = pk_fp8x4(f4, f5, f6, f7);
      *(uint2*)&xf8out[((size_t)node << 7) + c8 * 8] = r;
    }
    if (xbfout)
      *(short8*)&xbfout[(size_t)node * D + c8 * 8] = vv;
  }
}

// ---------------- tvec: target-edge GEMV, computed ONCE (unchanged) ----------------

__global__ __launch_bounds__(256) void tvec_kernel(const unsigned short* __restrict__ x,
                                                   const int* __restrict__ ep,
                                                   const float* __restrict__ W1,
                                                   const float* __restrict__ b1,
                                                   float* __restrict__ tvec) {
  __shared__ float su[128], sv[128];
  __shared__ float partb[2][128];
  int t = threadIdx.x;
  if (t < 128) {
    int u = ep[0], vv = ep[1];
    su[t] = bfu(x[(size_t)u * D + t]);
    sv[t] = bfu(x[(size_t)vv * D + t]);
  }
  __syncthreads();
  int j = t & 127, seg = t >> 7;
  const float* Wp = W1 + seg * 128 * D;
  float acc = 0.f;
#pragma unroll 8
  for (int k = 0; k < 128; ++k) {
    float f = seg ? fabsf(su[k] - sv[k]) : (su[k] + sv[k]);
    acc += f * Wp[k * D + j];
  }
  partb[seg][j] = acc;
  __syncthreads();
  if (t < 128) tvec[t] = b1[t] + partb[0][t] + partb[1][t];
}

// ---------------- predictor v9 (unchanged): 64 cands/block, swizzled staging ----------------

__global__ __launch_bounds__(256) void pred_kernel(const unsigned short* __restrict__ x,
                                                   const int* __restrict__ cand,
                                                   const short* __restrict__ Wf,
                                                   const float* __restrict__ tvec,
                                                   const float* __restrict__ w2,
                                                   const float* __restrict__ b2,
                                                   float* __restrict__ out) {
  __shared__ short sS[8192];   // 16 KB
  __shared__ short sD[8192];   // 16 KB
  int t = threadIdx.x;
  int blockRow = blockIdx.x * 64;
  int w = t >> 6, lane = t & 63;

  short8 U[4], V[4];
#pragma unroll
  for (int i = 0; i < 4; ++i) {
    int idx = t + i * 256;
    int c = blockRow + (idx >> 4);
    int2 uv = ((const int2*)cand)[c];
    int j8 = idx & 15;
    U[i] = *(const short8*)&x[(size_t)uv.x * D + j8 * 8];
    V[i] = *(const short8*)&x[(size_t)uv.y * D + j8 * 8];
  }
#pragma unroll
  for (int i = 0; i < 4; ++i) {
    int idx = t + i * 256;
    int m = idx >> 4, j8 = idx & 15;
    short8 ss, sd;
#pragma unroll
    for (int j = 0; j < 8; ++j) {
      float uf = bfu((unsigned short)U[i][j]);
      float vf = bfu((unsigned short)V[i][j]);
      ss[j] = f2bf(uf + vf);
      sd[j] = f2bf(fabsf(uf - vf));
    }
    int kk = j8 >> 2, qq = j8 & 3, mt = m >> 4, ln = (m & 15) | (qq << 4);
    int byte = ((mt * 4 + kk) * 64 + ln) * 16;
    byte = swz(byte);
    *(short8*)((char*)sS + byte) = ss;
    *(short8*)((char*)sD + byte) = sd;
  }
  __syncthreads();

  f32x4 acc[8] = {};
  const short* B0 = Wf + 6 * 16384;
  const short* B1 = Wf + 7 * 16384;
  for (int kk = 0; kk < 4; ++kk) {
    int byteA = swz(((w * 4 + kk) * 64 + lane) * 16);
    short8 a0 = *(short8*)((char*)sS + byteA);
    short8 a1 = *(short8*)((char*)sD + byteA);
#pragma unroll
    for (int nt = 0; nt < 8; ++nt) {
      short8 b0 = *(const short8*)&B0[((nt * 4 + kk) * 64 + lane) * 8];
      short8 b1f = *(const short8*)&B1[((nt * 4 + kk) * 64 + lane) * 8];
      acc[nt] = __builtin_amdgcn_mfma_f32_16x16x32_bf16(a0, b0, acc[nt], 0, 0, 0);
      acc[nt] = __builtin_amdgcn_mfma_f32_16x16x32_bf16(a1, b1f, acc[nt], 0, 0, 0);
    }
  }

  int colbase = lane & 15, rq = lane >> 4;
  float tv[8], w2v[8];
#pragma unroll
  for (int nt = 0; nt < 8; ++nt) {
    tv[nt] = tvec[nt * 16 + colbase];
    w2v[nt] = w2[nt * 16 + colbase];
  }
  float b2v = b2[0];
  {
    float part[4] = {0.f, 0.f, 0.f, 0.f};
#pragma unroll
    for (int nt = 0; nt < 8; ++nt)
#pragma unroll
      for (int r = 0; r < 4; ++r) {
        float h = acc[nt][r] + tv[nt];
        h = fmaxf(h, 0.f);
        part[r] += h * w2v[nt];
      }
#pragma unroll
    for (int r = 0; r < 4; ++r)
      for (int msk = 1; msk < 16; msk <<= 1)
        part[r] += __shfl_xor(part[r], msk, 64);
    if (colbase == 0) {
      int row0 = blockRow + w * 16 + rq * 4;
#pragma unroll
      for (int r = 0; r < 4; ++r) out[row0 + r] = part[r] + b2v;
    }
  }
}

// ---------------- launch ----------------

extern "C" void kernel_launch(void* const* d_in, const int* in_sizes, int n_in,
                              void* d_out, int out_size, void* d_ws, size_t ws_size,
                              hipStream_t stream) {
  const float* x_in = (const float*)d_in[0];
  const int* edge_index = (const int*)d_in[1];
  const int* ep = (const int*)d_in[2];
  const int* cand = (const int*)d_in[3];
  const float* gw1 = (const float*)d_in[4];
  const float* gb1 = (const float*)d_in[5];
  const float* gw2 = (const float*)d_in[6];
  const float* gb2 = (const float*)d_in[7];
  const float* pw1 = (const float*)d_in[8];
  const float* pb1 = (const float*)d_in[9];
  const float* pw2 = (const float*)d_in[10];
  const float* pb2 = (const float*)d_in[11];
  float* out = (float*)d_out;

  char* ws = (char*)d_ws;
  size_t off = 0;
  auto alloc = [&](size_t bytes) {
    void* p = ws + off;
    off += (bytes + 255) & ~(size_t)255;
    return p;
  };
  unsigned char* xf8A = (unsigned char*)alloc((size_t)ROWS * 128);  // fp8 row-major
  unsigned char* xf8B = (unsigned char*)alloc((size_t)ROWS * 128);
  unsigned short* xbf = (unsigned short*)alloc((size_t)ROWS * D * 2);  // bf16 (layer-3 out)
  int* pairs       = (int*)alloc((size_t)NB * BCAP * 4);
  int* csr         = (int*)alloc((size_t)NB * BCAP * 4);
  int2* rowBE      = (int2*)alloc((size_t)N_NODES * 8);
  int* bucket_cnt  = (int*)alloc((size_t)NB * 4);
  short* Wf        = (short*)alloc((size_t)8 * 16384 * 2);
  float* tvec      = (float*)alloc((size_t)D * 4);

  const int* src = edge_index;
  const int* dst = edge_index + N_EDGES;

  hipMemsetAsync(bucket_cnt, 0, (size_t)NB * 4, stream);

  prep_pass1<<<3581, 256, 0, stream>>>(gw1, gw2, pw1, Wf, x_in, xf8A, xf8B,
                                       src, dst, bucket_cnt, pairs);
  build_pass2<<<NB, 512, 0, stream>>>(pairs, bucket_cnt, rowBE, csr);

  const int gin_grid = N_NODES / 16;  // 3125
  gin_layer<<<gin_grid, 256, 0, stream>>>(xf8A, rowBE, csr, Wf + 0 * 16384, gb1 + 0 * D,
                                          Wf + 3 * 16384, gb2 + 0 * D, xf8B, nullptr);
  gin_layer<<<gin_grid, 256, 0, stream>>>(xf8B, rowBE, csr, Wf + 1 * 16384, gb1 + 1 * D,
                                          Wf + 4 * 16384, gb2 + 1 * D, xf8A, nullptr);
  gin_layer<<<gin_grid, 256, 0, stream>>>(xf8A, rowBE, csr, Wf + 2 * 16384, gb1 + 2 * D,
                                          Wf + 5 * 16384, gb2 + 2 * D, nullptr, xbf);

  tvec_kernel<<<1, 256, 0, stream>>>(xbf, ep, pw1, pb1, tvec);
  pred_kernel<<<N_CAND / 64, 256, 0, stream>>>(xbf, cand, Wf, tvec, pw2, pb2, out);
}

// Round 13
// 252.586 us; speedup vs baseline: 1.1248x; 1.1248x over previous
//
#include <hip/hip_runtime.h>

#define N_NODES 50000
#define N_EDGES 1600000
#define N_CAND  131072
#define D 128
#define ROWS 50176   // padded row count
#define NB 196       // coarse buckets (dst>>8)
#define BCAP 10240   // fixed per-bucket capacity (E[cnt]=8192, sigma~90)
#define LSTR 132     // LDS row stride (bf16 elems)
#define ZROW 50000   // zeroed row: /dev/null target for padded gather slots

typedef __attribute__((ext_vector_type(8))) short short8;
typedef __attribute__((ext_vector_type(4))) float f32x4;
typedef __attribute__((ext_vector_type(2))) float float2v;

__device__ inline short f2bf(float f) {
  unsigned u = __builtin_bit_cast(unsigned, f);
  u = (u + 0x7FFFu + ((u >> 16) & 1u)) >> 16;
  return (short)u;
}
__device__ inline float bfu(unsigned short h) { return __builtin_bit_cast(float, (unsigned)h << 16); }

// pack 4 f32 -> 4 fp8 e4m3 (one u32) via HW cvt
__device__ inline unsigned pk_fp8x4(float a, float b, float c, float d) {
  unsigned lo = 0, hi = 0;
  asm("v_cvt_pk_fp8_f32 %0, %1, %2" : "+v"(lo) : "v"(a), "v"(b));
  asm("v_cvt_pk_fp8_f32 %0, %1, %2" : "+v"(hi) : "v"(c), "v"(d));
  return (lo & 0xFFFFu) | (hi << 16);
}

// LDS staging swizzle: spreads the 16 (kk,qq) slots of one row across 8 bank-quads
__device__ inline int swz(int b) { return b ^ (((b >> 8) & 7) << 4); }

// ---------------- prep + pass1 merged (x written row-major FP8; block 3580
// zeroes the ZROW rows, replacing two hipMemsetAsync dispatches) ----------------

__global__ __launch_bounds__(256) void prep_pass1(const float* __restrict__ gw1,
                                                  const float* __restrict__ gw2,
                                                  const float* __restrict__ pw1,
                                                  short* __restrict__ Wf,
                                                  const float* __restrict__ x,
                                                  unsigned char* __restrict__ y8,
                                                  unsigned char* __restrict__ y8b,
                                                  const int* __restrict__ src,
                                                  const int* __restrict__ dst,
                                                  int* __restrict__ bucket_cnt,
                                                  int* __restrict__ pairs) {
  int b = blockIdx.x;
  int t = threadIdx.x;
  if (b == 3580) {
    if (t < 32) {
      *(unsigned*)&y8[(size_t)ZROW * 128 + t * 4] = 0u;
      *(unsigned*)&y8b[(size_t)ZROW * 128 + t * 4] = 0u;
    }
    return;
  }
  if (b < 64) {
    int tid = b * 256 + t;  // 0..16383
    int img = tid >> 11, idx = tid & 2047;
    const float* W;
    if (img < 3) W = gw1 + img * 16384;
    else if (img < 6) W = gw2 + (img - 3) * 16384;
    else W = pw1 + (256 + (img - 6) * 128) * 128;
    int n = idx & 127, k8 = idx >> 7;
    short8 s;
#pragma unroll
    for (int j = 0; j < 8; ++j) s[j] = f2bf(W[(k8 * 8 + j) * 128 + n]);
    int kk = k8 >> 2, q = k8 & 3, nt = n >> 4, ln = (n & 15) | (q << 4);
    *(short8*)&Wf[img * 16384 + ((nt * 4 + kk) * 64 + ln) * 8] = s;
  } else if (b < 3189) {
    int tid = (b - 64) * 256 + t;       // 0..799999 ; 8 floats each
    size_t base = (size_t)tid * 8;
    float4 v0 = *(const float4*)&x[base];
    float4 v1 = *(const float4*)&x[base + 4];
    uint2 r;
    r.x = pk_fp8x4(v0.x, v0.y, v0.z, v0.w);
    r.y = pk_fp8x4(v1.x, v1.y, v1.z, v1.w);
    *(uint2*)&y8[base] = r;             // row-major fp8: node*128 + c8*8
  } else {
    __shared__ int lcnt[NB];
    __shared__ int loff[NB];
    __shared__ int gbase[NB];
    __shared__ int scanbuf[256];
    __shared__ int stage[4096];
    int e0 = (b - 3189) * 4096;
    for (int i = t; i < NB; i += 256) lcnt[i] = 0;
    __syncthreads();
    int d[16], s[16], r[16];
#pragma unroll
    for (int i = 0; i < 16; ++i) {
      int e = e0 + i * 256 + t;
      if (e < N_EDGES) {
        d[i] = dst[e]; s[i] = src[e];
        r[i] = atomicAdd(&lcnt[d[i] >> 8], 1);
      } else d[i] = -1;
    }
    __syncthreads();
    {
      int v = (t < NB) ? lcnt[t] : 0;
      scanbuf[t] = v;
      __syncthreads();
      for (int off = 1; off < 256; off <<= 1) {
        int add = (t >= off) ? scanbuf[t - off] : 0;
        __syncthreads();
        scanbuf[t] += add;
        __syncthreads();
      }
      if (t < NB) {
        loff[t] = scanbuf[t] - v;
        gbase[t] = v ? atomicAdd(&bucket_cnt[t], v) : 0;
      }
    }
    __syncthreads();
#pragma unroll
    for (int i = 0; i < 16; ++i) {
      if (d[i] >= 0) {
        int bb = d[i] >> 8;
        stage[loff[bb] + r[i]] = (s[i] << 8) | (d[i] & 255);
      }
    }
    __syncthreads();
    int w = t >> 6, lane = t & 63;
    for (int bb = w; bb < NB; bb += 4) {
      int c = lcnt[bb], lo = loff[bb], gb = bb * BCAP + gbase[bb];
      for (int k = lane; k < c; k += 64) pairs[gb + k] = stage[lo + k];
    }
  }
}

// ---------------- pass2: within-bucket counting sort (unchanged) ----------------

__global__ __launch_bounds__(512) void build_pass2(const int* __restrict__ pairs,
                                                   const int* __restrict__ bucket_cnt,
                                                   int2* __restrict__ rowBE,
                                                   int* __restrict__ csr) {
  __shared__ int cnt_s[256];
  __shared__ int buf[256];
  __shared__ int ssrc[BCAP];
  int t = threadIdx.x;
  int b = blockIdx.x;
  int cnt = bucket_cnt[b];
  int gbase = b * BCAP;
  const int* pp = pairs + gbase;
  if (t < 256) cnt_s[t] = 0;
  __syncthreads();
  for (int i = t; i < cnt; i += 512) atomicAdd(&cnt_s[pp[i] & 255], 1);
  __syncthreads();
  int v = 0;
  if (t < 256) { v = cnt_s[t]; buf[t] = v; }
  __syncthreads();
  for (int off = 1; off < 256; off <<= 1) {
    int add = (t >= off && t < 256) ? buf[t - off] : 0;
    __syncthreads();
    if (t < 256) buf[t] += add;
    __syncthreads();
  }
  if (t < 256) {
    int excl = buf[t] - v;
    int node = (b << 8) + t;
    if (node < N_NODES) rowBE[node] = make_int2(gbase + excl, gbase + excl + v);
    cnt_s[t] = excl;
  }
  __syncthreads();
  for (int i = t; i < cnt; i += 512) {
    int p = pp[i];
    int pos = atomicAdd(&cnt_s[p & 255], 1);
    ssrc[pos] = p >> 8;
  }
  __syncthreads();
  for (int i = t; i < cnt; i += 512) csr[gbase + i] = ssrc[i];
}

// ---------------- fused GIN layer v11 (reverted, known-good ~36us): fp8 gather,
// 2 edges per 64-lane dword load, ds_bpermute idx distribution; ALL per-node
// latency chains (rowBE, csr chunk, own row) prefetched up front. ----------------

#if __has_builtin(__builtin_amdgcn_cvt_pk_f32_fp8)
#define FADD2(u_) { float2v lo_ = __builtin_amdgcn_cvt_pk_f32_fp8((int)(u_), false); \
                    float2v hi_ = __builtin_amdgcn_cvt_pk_f32_fp8((int)(u_), true);  \
                    a01 += lo_; a23 += hi_; }
#else
#define FADD2(u_) { float2v lo_, hi_; unsigned h_ = (u_) >> 16;           \
    asm("v_cvt_pk_f32_fp8 %0, %1" : "=v"(lo_) : "v"(u_));                 \
    asm("v_cvt_pk_f32_fp8 %0, %1" : "=v"(hi_) : "v"(h_));                 \
    a01 += lo_; a23 += hi_; }
#endif

#define LADDER(sidx_v, cnt_v) {                                                     \
    int np_ = ((cnt_v) + 1) >> 1;                                                   \
    int ii_ = 0;                                                                    \
    for (; ii_ + 16 <= np_; ii_ += 16) {                                            \
      unsigned v_[16];                                                              \
      _Pragma("unroll")                                                             \
      for (int j_ = 0; j_ < 16; ++j_) {                                             \
        int row_ = __builtin_amdgcn_ds_bpermute(vb + (ii_ + j_) * 8, (sidx_v));     \
        v_[j_] = *(const unsigned*)(xb + ((size_t)(unsigned)row_ << 7) + colb);     \
      }                                                                             \
      _Pragma("unroll")                                                             \
      for (int j_ = 0; j_ < 16; ++j_) FADD2(v_[j_]);                                \
    }                                                                               \
    for (; ii_ + 8 <= np_; ii_ += 8) {                                              \
      unsigned v_[8];                                                               \
      _Pragma("unroll")                                                             \
      for (int j_ = 0; j_ < 8; ++j_) {                                              \
        int row_ = __builtin_amdgcn_ds_bpermute(vb + (ii_ + j_) * 8, (sidx_v));     \
        v_[j_] = *(const unsigned*)(xb + ((size_t)(unsigned)row_ << 7) + colb);     \
      }                                                                             \
      _Pragma("unroll")                                                             \
      for (int j_ = 0; j_ < 8; ++j_) FADD2(v_[j_]);                                 \
    }                                                                               \
    for (; ii_ + 4 <= np_; ii_ += 4) {                                              \
      unsigned v_[4];                                                               \
      _Pragma("unroll")                                                             \
      for (int j_ = 0; j_ < 4; ++j_) {                                              \
        int row_ = __builtin_amdgcn_ds_bpermute(vb + (ii_ + j_) * 8, (sidx_v));     \
        v_[j_] = *(const unsigned*)(xb + ((size_t)(unsigned)row_ << 7) + colb);     \
      }                                                                             \
      _Pragma("unroll")                                                             \
      for (int j_ = 0; j_ < 4; ++j_) FADD2(v_[j_]);                                 \
    }                                                                               \
    for (; ii_ < np_; ++ii_) {                                                      \
      int row_ = __builtin_amdgcn_ds_bpermute(vb + ii_ * 8, (sidx_v));              \
      unsigned v_ = *(const unsigned*)(xb + ((size_t)(unsigned)row_ << 7) + colb);  \
      FADD2(v_);                                                                    \
    }                                                                               \
  }

__global__ __launch_bounds__(256) void gin_layer(const unsigned char* __restrict__ xf8,
                                                 const int2* __restrict__ rowBE,
                                                 const int* __restrict__ csr,
                                                 const short* __restrict__ B1f,
                                                 const float* __restrict__ b1,
                                                 const short* __restrict__ B2f,
                                                 const float* __restrict__ b2,
                                                 unsigned char* __restrict__ xf8out,
                                                 unsigned short* __restrict__ xbfout) {
  __shared__ short hbuf[16 * LSTR];   // 4224 B
  int t = threadIdx.x;
  int w = t >> 6, lane = t & 63;
  int vb = (lane & 32) >> 3;          // half*4: bpermute byte-addr base
  int colb = (lane & 31) << 2;        // byte column within 128B fp8 row
  int node0 = blockIdx.x * 16;        // grid 3125: exact cover of 50000
  const char* xb = (const char*)xf8;

  // ---- prefetch ALL per-node latency chains up front (independent batches) ----
  int2 be_[4];
#pragma unroll
  for (int i = 0; i < 4; ++i) be_[i] = rowBE[node0 + w * 4 + i];
  int sidx_[4];
#pragma unroll
  for (int i = 0; i < 4; ++i)
    sidx_[i] = (be_[i].x + lane < be_[i].y) ? csr[be_[i].x + lane] : ZROW;
  unsigned sv_[4];
#pragma unroll
  for (int i = 0; i < 4; ++i)
    sv_[i] = *(const unsigned*)(xb + ((size_t)(node0 + w * 4 + i) << 7) + colb);

#pragma unroll
  for (int i = 0; i < 4; ++i) {
    int node = node0 + w * 4 + i;
    int beg = be_[i].x, end = be_[i].y;
    float2v a01 = {0.f, 0.f}, a23 = {0.f, 0.f};

    {
      int cnt0 = min(64, end - beg);
      LADDER(sidx_[i], cnt0);
    }
#pragma unroll 1
    for (int e = beg + 64; e < end; e += 64) {   // rare: degree > 64
      int cnt = min(64, end - e);
      int sidx = (e + lane < end) ? csr[e + lane] : ZROW;
      LADDER(sidx, cnt);
    }

    // halves hold partial sums of the same 4 dims -> combine
    a01[0] += __shfl_xor(a01[0], 32, 64);
    a01[1] += __shfl_xor(a01[1], 32, 64);
    a23[0] += __shfl_xor(a23[0], 32, 64);
    a23[1] += __shfl_xor(a23[1], 32, 64);

    if (lane < 32) {
      // add own row (h = x + agg), write bf16 into hbuf (dims 4*lane..+3)
      unsigned sv = sv_[i];
      FADD2(sv);
      uint2 r;
      r.x = (unsigned)(unsigned short)f2bf(a01[0]) | ((unsigned)(unsigned short)f2bf(a01[1]) << 16);
      r.y = (unsigned)(unsigned short)f2bf(a23[0]) | ((unsigned)(unsigned short)f2bf(a23[1]) << 16);
      *(uint2*)&hbuf[(w * 4 + i) * LSTR + lane * 4] = r;
    }
  }
  __syncthreads();

  int q = lane >> 4, m = lane & 15;
  short8 a0f[4];
#pragma unroll
  for (int kk = 0; kk < 4; ++kk)
    a0f[kk] = *(short8*)&hbuf[m * LSTR + kk * 32 + q * 8];
  __syncthreads();

  f32x4 acc[2] = {};
#pragma unroll
  for (int kk = 0; kk < 4; ++kk)
#pragma unroll
    for (int j = 0; j < 2; ++j) {
      int nt = w * 2 + j;
      short8 bf = *(const short8*)&B1f[((nt * 4 + kk) * 64 + lane) * 8];
      acc[j] = __builtin_amdgcn_mfma_f32_16x16x32_bf16(a0f[kk], bf, acc[j], 0, 0, 0);
    }
#pragma unroll
  for (int j = 0; j < 2; ++j) {
    int nt = w * 2 + j;
    float bv = b1[nt * 16 + m];
#pragma unroll
    for (int r = 0; r < 4; ++r)
      hbuf[(q * 4 + r) * LSTR + nt * 16 + m] = f2bf(fmaxf(acc[j][r] + bv, 0.f));
  }
  __syncthreads();

  short8 a1f[4];
#pragma unroll
  for (int kk = 0; kk < 4; ++kk)
    a1f[kk] = *(short8*)&hbuf[m * LSTR + kk * 32 + q * 8];
  __syncthreads();

  f32x4 acc2v[2] = {};
#pragma unroll
  for (int kk = 0; kk < 4; ++kk)
#pragma unroll
    for (int j = 0; j < 2; ++j) {
      int nt = w * 2 + j;
      short8 bf = *(const short8*)&B2f[((nt * 4 + kk) * 64 + lane) * 8];
      acc2v[j] = __builtin_amdgcn_mfma_f32_16x16x32_bf16(a1f[kk], bf, acc2v[j], 0, 0, 0);
    }
#pragma unroll
  for (int j = 0; j < 2; ++j) {
    int nt = w * 2 + j;
    float bv = b2[nt * 16 + m];
#pragma unroll
    for (int r = 0; r < 4; ++r)
      hbuf[(q * 4 + r) * LSTR + nt * 16 + m] = f2bf(acc2v[j][r] + bv);
  }
  __syncthreads();

  {
    int row = t >> 4, c8 = t & 15;
    short8 vv = *(short8*)&hbuf[row * LSTR + c8 * 8];
    int node = node0 + row;
    if (xf8out) {
      float f0 = bfu((unsigned short)vv[0]), f1 = bfu((unsigned short)vv[1]);
      float f2 = bfu((unsigned short)vv[2]), f3 = bfu((unsigned short)vv[3]);
      float f4 = bfu((unsigned short)vv[4]), f5 = bfu((unsigned short)vv[5]);
      float f6 = bfu((unsigned short)vv[6]), f7 = bfu((unsigned short)vv[7]);
      uint2 r;
      r.x = pk_fp8x4(f0, f1, f2, f3);
      r.y = pk_fp8x4(f4, f5, f6, f7);
      *(uint2*)&xf8out[((size_t)node << 7) + c8 * 8] = r;
    }
    if (xbfout)
      *(short8*)&xbfout[(size_t)node * D + c8 * 8] = vv;
  }
}

// ---------------- tvec: target-edge GEMV, computed ONCE (unchanged) ----------------

__global__ __launch_bounds__(256) void tvec_kernel(const unsigned short* __restrict__ x,
                                                   const int* __restrict__ ep,
                                                   const float* __restrict__ W1,
                                                   const float* __restrict__ b1,
                                                   float* __restrict__ tvec) {
  __shared__ float su[128], sv[128];
  __shared__ float partb[2][128];
  int t = threadIdx.x;
  if (t < 128) {
    int u = ep[0], vv = ep[1];
    su[t] = bfu(x[(size_t)u * D + t]);
    sv[t] = bfu(x[(size_t)vv * D + t]);
  }
  __syncthreads();
  int j = t & 127, seg = t >> 7;
  const float* Wp = W1 + seg * 128 * D;
  float acc = 0.f;
#pragma unroll 8
  for (int k = 0; k < 128; ++k) {
    float f = seg ? fabsf(su[k] - sv[k]) : (su[k] + sv[k]);
    acc += f * Wp[k * D + j];
  }
  partb[seg][j] = acc;
  __syncthreads();
  if (t < 128) tvec[t] = b1[t] + partb[0][t] + partb[1][t];
}

// ---------------- predictor v9 (unchanged): 64 cands/block, swizzled staging ----------------

__global__ __launch_bounds__(256) void pred_kernel(const unsigned short* __restrict__ x,
                                                   const int* __restrict__ cand,
                                                   const short* __restrict__ Wf,
                                                   const float* __restrict__ tvec,
                                                   const float* __restrict__ w2,
                                                   const float* __restrict__ b2,
                                                   float* __restrict__ out) {
  __shared__ short sS[8192];   // 16 KB
  __shared__ short sD[8192];   // 16 KB
  int t = threadIdx.x;
  int blockRow = blockIdx.x * 64;
  int w = t >> 6, lane = t & 63;

  short8 U[4], V[4];
#pragma unroll
  for (int i = 0; i < 4; ++i) {
    int idx = t + i * 256;
    int c = blockRow + (idx >> 4);
    int2 uv = ((const int2*)cand)[c];
    int j8 = idx & 15;
    U[i] = *(const short8*)&x[(size_t)uv.x * D + j8 * 8];
    V[i] = *(const short8*)&x[(size_t)uv.y * D + j8 * 8];
  }
#pragma unroll
  for (int i = 0; i < 4; ++i) {
    int idx = t + i * 256;
    int m = idx >> 4, j8 = idx & 15;
    short8 ss, sd;
#pragma unroll
    for (int j = 0; j < 8; ++j) {
      float uf = bfu((unsigned short)U[i][j]);
      float vf = bfu((unsigned short)V[i][j]);
      ss[j] = f2bf(uf + vf);
      sd[j] = f2bf(fabsf(uf - vf));
    }
    int kk = j8 >> 2, qq = j8 & 3, mt = m >> 4, ln = (m & 15) | (qq << 4);
    int byte = ((mt * 4 + kk) * 64 + ln) * 16;
    byte = swz(byte);
    *(short8*)((char*)sS + byte) = ss;
    *(short8*)((char*)sD + byte) = sd;
  }
  __syncthreads();

  f32x4 acc[8] = {};
  const short* B0 = Wf + 6 * 16384;
  const short* B1 = Wf + 7 * 16384;
  for (int kk = 0; kk < 4; ++kk) {
    int byteA = swz(((w * 4 + kk) * 64 + lane) * 16);
    short8 a0 = *(short8*)((char*)sS + byteA);
    short8 a1 = *(short8*)((char*)sD + byteA);
#pragma unroll
    for (int nt = 0; nt < 8; ++nt) {
      short8 b0 = *(const short8*)&B0[((nt * 4 + kk) * 64 + lane) * 8];
      short8 b1f = *(const short8*)&B1[((nt * 4 + kk) * 64 + lane) * 8];
      acc[nt] = __builtin_amdgcn_mfma_f32_16x16x32_bf16(a0, b0, acc[nt], 0, 0, 0);
      acc[nt] = __builtin_amdgcn_mfma_f32_16x16x32_bf16(a1, b1f, acc[nt], 0, 0, 0);
    }
  }

  int colbase = lane & 15, rq = lane >> 4;
  float tv[8], w2v[8];
#pragma unroll
  for (int nt = 0; nt < 8; ++nt) {
    tv[nt] = tvec[nt * 16 + colbase];
    w2v[nt] = w2[nt * 16 + colbase];
  }
  float b2v = b2[0];
  {
    float part[4] = {0.f, 0.f, 0.f, 0.f};
#pragma unroll
    for (int nt = 0; nt < 8; ++nt)
#pragma unroll
      for (int r = 0; r < 4; ++r) {
        float h = acc[nt][r] + tv[nt];
        h = fmaxf(h, 0.f);
        part[r] += h * w2v[nt];
      }
#pragma unroll
    for (int r = 0; r < 4; ++r)
      for (int msk = 1; msk < 16; msk <<= 1)
        part[r] += __shfl_xor(part[r], msk, 64);
    if (colbase == 0) {
      int row0 = blockRow + w * 16 + rq * 4;
#pragma unroll
      for (int r = 0; r < 4; ++r) out[row0 + r] = part[r] + b2v;
    }
  }
}

// ---------------- launch ----------------

extern "C" void kernel_launch(void* const* d_in, const int* in_sizes, int n_in,
                              void* d_out, int out_size, void* d_ws, size_t ws_size,
                              hipStream_t stream) {
  const float* x_in = (const float*)d_in[0];
  const int* edge_index = (const int*)d_in[1];
  const int* ep = (const int*)d_in[2];
  const int* cand = (const int*)d_in[3];
  const float* gw1 = (const float*)d_in[4];
  const float* gb1 = (const float*)d_in[5];
  const float* gw2 = (const float*)d_in[6];
  const float* gb2 = (const float*)d_in[7];
  const float* pw1 = (const float*)d_in[8];
  const float* pb1 = (const float*)d_in[9];
  const float* pw2 = (const float*)d_in[10];
  const float* pb2 = (const float*)d_in[11];
  float* out = (float*)d_out;

  char* ws = (char*)d_ws;
  size_t off = 0;
  auto alloc = [&](size_t bytes) {
    void* p = ws + off;
    off += (bytes + 255) & ~(size_t)255;
    return p;
  };
  unsigned char* xf8A = (unsigned char*)alloc((size_t)ROWS * 128);  // fp8 row-major
  unsigned char* xf8B = (unsigned char*)alloc((size_t)ROWS * 128);
  unsigned short* xbf = (unsigned short*)alloc((size_t)ROWS * D * 2);  // bf16 (layer-3 out)
  int* pairs       = (int*)alloc((size_t)NB * BCAP * 4);
  int* csr         = (int*)alloc((size_t)NB * BCAP * 4);
  int2* rowBE      = (int2*)alloc((size_t)N_NODES * 8);
  int* bucket_cnt  = (int*)alloc((size_t)NB * 4);
  short* Wf        = (short*)alloc((size_t)8 * 16384 * 2);
  float* tvec      = (float*)alloc((size_t)D * 4);

  const int* src = edge_index;
  const int* dst = edge_index + N_EDGES;

  hipMemsetAsync(bucket_cnt, 0, (size_t)NB * 4, stream);

  prep_pass1<<<3581, 256, 0, stream>>>(gw1, gw2, pw1, Wf, x_in, xf8A, xf8B,
                                       src, dst, bucket_cnt, pairs);
  build_pass2<<<NB, 512, 0, stream>>>(pairs, bucket_cnt, rowBE, csr);

  const int gin_grid = N_NODES / 16;  // 3125
  gin_layer<<<gin_grid, 256, 0, stream>>>(xf8A, rowBE, csr, Wf + 0 * 16384, gb1 + 0 * D,
                                          Wf + 3 * 16384, gb2 + 0 * D, xf8B, nullptr);
  gin_layer<<<gin_grid, 256, 0, stream>>>(xf8B, rowBE, csr, Wf + 1 * 16384, gb1 + 1 * D,
                                          Wf + 4 * 16384, gb2 + 1 * D, xf8A, nullptr);
  gin_layer<<<gin_grid, 256, 0, stream>>>(xf8A, rowBE, csr, Wf + 2 * 16384, gb1 + 2 * D,
                                          Wf + 5 * 16384, gb2 + 2 * D, nullptr, xbf);

  tvec_kernel<<<1, 256, 0, stream>>>(xbf, ep, pw1, pb1, tvec);
  pred_kernel<<<N_CAND / 64, 256, 0, stream>>>(xbf, cand, Wf, tvec, pw2, pb2, out);
}

// Round 16
// 250.385 us; speedup vs baseline: 1.1347x; 1.0088x over previous
//
#include <hip/hip_runtime.h>

#define N_NODES 50000
#define N_EDGES 1600000
#define N_CAND  131072
#define D 128
#define ROWS 50176   // padded row count
#define NB 196       // coarse buckets (dst>>8)
#define BCAP 10240   // fixed per-bucket capacity (E[cnt]=8192, sigma~90)
#define LSTR 132     // LDS row stride (bf16 elems)
#define ZROW 50000   // zeroed row: /dev/null target for padded gather slots

typedef __attribute__((ext_vector_type(8))) short short8;
typedef __attribute__((ext_vector_type(4))) float f32x4;
typedef __attribute__((ext_vector_type(2))) float float2v;

__device__ inline short f2bf(float f) {
  unsigned u = __builtin_bit_cast(unsigned, f);
  u = (u + 0x7FFFu + ((u >> 16) & 1u)) >> 16;
  return (short)u;
}
__device__ inline float bfu(unsigned short h) { return __builtin_bit_cast(float, (unsigned)h << 16); }

// pack 4 f32 -> 4 fp8 e4m3 (one u32) via HW cvt
__device__ inline unsigned pk_fp8x4(float a, float b, float c, float d) {
  unsigned lo = 0, hi = 0;
  asm("v_cvt_pk_fp8_f32 %0, %1, %2" : "+v"(lo) : "v"(a), "v"(b));
  asm("v_cvt_pk_fp8_f32 %0, %1, %2" : "+v"(hi) : "v"(c), "v"(d));
  return (lo & 0xFFFFu) | (hi << 16);
}

// unpack 2 fp8 e4m3 (lo or hi 16-bit pair of u) -> 2 f32; HI must be compile-time
template <bool HI>
__device__ inline float2v cvt2(unsigned u) {
#if __has_builtin(__builtin_amdgcn_cvt_pk_f32_fp8)
  return __builtin_amdgcn_cvt_pk_f32_fp8((int)u, HI);
#else
  float2v r; unsigned s = HI ? (u >> 16) : u;
  asm("v_cvt_pk_f32_fp8 %0, %1" : "=v"(r) : "v"(s));
  return r;
#endif
}

// LDS staging swizzle: spreads the 16 (kk,qq) slots of one row across 8 bank-quads
__device__ inline int swz(int b) { return b ^ (((b >> 8) & 7) << 4); }

// ---------------- prep + pass1 merged (x written row-major FP8; block 3580
// zeroes the ZROW rows, replacing two hipMemsetAsync dispatches) ----------------

__global__ __launch_bounds__(256) void prep_pass1(const float* __restrict__ gw1,
                                                  const float* __restrict__ gw2,
                                                  const float* __restrict__ pw1,
                                                  short* __restrict__ Wf,
                                                  const float* __restrict__ x,
                                                  unsigned char* __restrict__ y8,
                                                  unsigned char* __restrict__ y8b,
                                                  const int* __restrict__ src,
                                                  const int* __restrict__ dst,
                                                  int* __restrict__ bucket_cnt,
                                                  int* __restrict__ pairs) {
  int b = blockIdx.x;
  int t = threadIdx.x;
  if (b == 3580) {
    if (t < 32) {
      *(unsigned*)&y8[(size_t)ZROW * 128 + t * 4] = 0u;
      *(unsigned*)&y8b[(size_t)ZROW * 128 + t * 4] = 0u;
    }
    return;
  }
  if (b < 64) {
    int tid = b * 256 + t;  // 0..16383
    int img = tid >> 11, idx = tid & 2047;
    const float* W;
    if (img < 3) W = gw1 + img * 16384;
    else if (img < 6) W = gw2 + (img - 3) * 16384;
    else W = pw1 + (256 + (img - 6) * 128) * 128;
    int n = idx & 127, k8 = idx >> 7;
    short8 s;
#pragma unroll
    for (int j = 0; j < 8; ++j) s[j] = f2bf(W[(k8 * 8 + j) * 128 + n]);
    int kk = k8 >> 2, q = k8 & 3, nt = n >> 4, ln = (n & 15) | (q << 4);
    *(short8*)&Wf[img * 16384 + ((nt * 4 + kk) * 64 + ln) * 8] = s;
  } else if (b < 3189) {
    int tid = (b - 64) * 256 + t;       // 0..799999 ; 8 floats each
    size_t base = (size_t)tid * 8;
    float4 v0 = *(const float4*)&x[base];
    float4 v1 = *(const float4*)&x[base + 4];
    uint2 r;
    r.x = pk_fp8x4(v0.x, v0.y, v0.z, v0.w);
    r.y = pk_fp8x4(v1.x, v1.y, v1.z, v1.w);
    *(uint2*)&y8[base] = r;             // row-major fp8: node*128 + c8*8
  } else {
    __shared__ int lcnt[NB];
    __shared__ int loff[NB];
    __shared__ int gbase[NB];
    __shared__ int scanbuf[256];
    __shared__ int stage[4096];
    int e0 = (b - 3189) * 4096;
    for (int i = t; i < NB; i += 256) lcnt[i] = 0;
    __syncthreads();
    int d[16], s[16], r[16];
#pragma unroll
    for (int i = 0; i < 16; ++i) {
      int e = e0 + i * 256 + t;
      if (e < N_EDGES) {
        d[i] = dst[e]; s[i] = src[e];
        r[i] = atomicAdd(&lcnt[d[i] >> 8], 1);
      } else d[i] = -1;
    }
    __syncthreads();
    {
      int v = (t < NB) ? lcnt[t] : 0;
      scanbuf[t] = v;
      __syncthreads();
      for (int off = 1; off < 256; off <<= 1) {
        int add = (t >= off) ? scanbuf[t - off] : 0;
        __syncthreads();
        scanbuf[t] += add;
        __syncthreads();
      }
      if (t < NB) {
        loff[t] = scanbuf[t] - v;
        gbase[t] = v ? atomicAdd(&bucket_cnt[t], v) : 0;
      }
    }
    __syncthreads();
#pragma unroll
    for (int i = 0; i < 16; ++i) {
      if (d[i] >= 0) {
        int bb = d[i] >> 8;
        stage[loff[bb] + r[i]] = (s[i] << 8) | (d[i] & 255);
      }
    }
    __syncthreads();
    int w = t >> 6, lane = t & 63;
    for (int bb = w; bb < NB; bb += 4) {
      int c = lcnt[bb], lo = loff[bb], gb = bb * BCAP + gbase[bb];
      for (int k = lane; k < c; k += 64) pairs[gb + k] = stage[lo + k];
    }
  }
}

// ---------------- pass2: within-bucket counting sort (unchanged) ----------------

__global__ __launch_bounds__(512) void build_pass2(const int* __restrict__ pairs,
                                                   const int* __restrict__ bucket_cnt,
                                                   int2* __restrict__ rowBE,
                                                   int* __restrict__ csr) {
  __shared__ int cnt_s[256];
  __shared__ int buf[256];
  __shared__ int ssrc[BCAP];
  int t = threadIdx.x;
  int b = blockIdx.x;
  int cnt = bucket_cnt[b];
  int gbase = b * BCAP;
  const int* pp = pairs + gbase;
  if (t < 256) cnt_s[t] = 0;
  __syncthreads();
  for (int i = t; i < cnt; i += 512) atomicAdd(&cnt_s[pp[i] & 255], 1);
  __syncthreads();
  int v = 0;
  if (t < 256) { v = cnt_s[t]; buf[t] = v; }
  __syncthreads();
  for (int off = 1; off < 256; off <<= 1) {
    int add = (t >= off && t < 256) ? buf[t - off] : 0;
    __syncthreads();
    if (t < 256) buf[t] += add;
    __syncthreads();
  }
  if (t < 256) {
    int excl = buf[t] - v;
    int node = (b << 8) + t;
    if (node < N_NODES) rowBE[node] = make_int2(gbase + excl, gbase + excl + v);
    cnt_s[t] = excl;
  }
  __syncthreads();
  for (int i = t; i < cnt; i += 512) {
    int p = pp[i];
    int pos = atomicAdd(&cnt_s[p & 255], 1);
    ssrc[pos] = p >> 8;
  }
  __syncthreads();
  for (int i = t; i < cnt; i += 512) csr[gbase + i] = ssrc[i];
}

// ---------------- fused GIN layer v11 (unchanged, known-good ~36us): fp8 gather,
// 2 edges per 64-lane dword load, ds_bpermute idx distribution; ALL per-node
// latency chains (rowBE, csr chunk, own row) prefetched up front. ----------------

#define FADD2(u_) { float2v lo_ = cvt2<false>(u_); \
                    float2v hi_ = cvt2<true>(u_);  \
                    a01 += lo_; a23 += hi_; }

#define LADDER(sidx_v, cnt_v) {                                                     \
    int np_ = ((cnt_v) + 1) >> 1;                                                   \
    int ii_ = 0;                                                                    \
    for (; ii_ + 16 <= np_; ii_ += 16) {                                            \
      unsigned v_[16];                                                              \
      _Pragma("unroll")                                                             \
      for (int j_ = 0; j_ < 16; ++j_) {                                             \
        int row_ = __builtin_amdgcn_ds_bpermute(vb + (ii_ + j_) * 8, (sidx_v));     \
        v_[j_] = *(const unsigned*)(xb + ((size_t)(unsigned)row_ << 7) + colb);     \
      }                                                                             \
      _Pragma("unroll")                                                             \
      for (int j_ = 0; j_ < 16; ++j_) FADD2(v_[j_]);                                \
    }                                                                               \
    for (; ii_ + 8 <= np_; ii_ += 8) {                                              \
      unsigned v_[8];                                                               \
      _Pragma("unroll")                                                             \
      for (int j_ = 0; j_ < 8; ++j_) {                                              \
        int row_ = __builtin_amdgcn_ds_bpermute(vb + (ii_ + j_) * 8, (sidx_v));     \
        v_[j_] = *(const unsigned*)(xb + ((size_t)(unsigned)row_ << 7) + colb);     \
      }                                                                             \
      _Pragma("unroll")                                                             \
      for (int j_ = 0; j_ < 8; ++j_) FADD2(v_[j_]);                                 \
    }                                                                               \
    for (; ii_ + 4 <= np_; ii_ += 4) {                                              \
      unsigned v_[4];                                                               \
      _Pragma("unroll")                                                             \
      for (int j_ = 0; j_ < 4; ++j_) {                                              \
        int row_ = __builtin_amdgcn_ds_bpermute(vb + (ii_ + j_) * 8, (sidx_v));     \
        v_[j_] = *(const unsigned*)(xb + ((size_t)(unsigned)row_ << 7) + colb);     \
      }                                                                             \
      _Pragma("unroll")                                                             \
      for (int j_ = 0; j_ < 4; ++j_) FADD2(v_[j_]);                                 \
    }                                                                               \
    for (; ii_ < np_; ++ii_) {                                                      \
      int row_ = __builtin_amdgcn_ds_bpermute(vb + ii_ * 8, (sidx_v));              \
      unsigned v_ = *(const unsigned*)(xb + ((size_t)(unsigned)row_ << 7) + colb);  \
      FADD2(v_);                                                                    \
    }                                                                               \
  }

__global__ __launch_bounds__(256) void gin_layer(const unsigned char* __restrict__ xf8,
                                                 const int2* __restrict__ rowBE,
                                                 const int* __restrict__ csr,
                                                 const short* __restrict__ B1f,
                                                 const float* __restrict__ b1,
                                                 const short* __restrict__ B2f,
                                                 const float* __restrict__ b2,
                                                 unsigned char* __restrict__ xf8out,
                                                 unsigned short* __restrict__ xbfout) {
  __shared__ short hbuf[16 * LSTR];   // 4224 B
  int t = threadIdx.x;
  int w = t >> 6, lane = t & 63;
  int vb = (lane & 32) >> 3;          // half*4: bpermute byte-addr base
  int colb = (lane & 31) << 2;        // byte column within 128B fp8 row
  int node0 = blockIdx.x * 16;        // grid 3125: exact cover of 50000
  const char* xb = (const char*)xf8;

  // ---- prefetch ALL per-node latency chains up front (independent batches) ----
  int2 be_[4];
#pragma unroll
  for (int i = 0; i < 4; ++i) be_[i] = rowBE[node0 + w * 4 + i];
  int sidx_[4];
#pragma unroll
  for (int i = 0; i < 4; ++i)
    sidx_[i] = (be_[i].x + lane < be_[i].y) ? csr[be_[i].x + lane] : ZROW;
  unsigned sv_[4];
#pragma unroll
  for (int i = 0; i < 4; ++i)
    sv_[i] = *(const unsigned*)(xb + ((size_t)(node0 + w * 4 + i) << 7) + colb);

#pragma unroll
  for (int i = 0; i < 4; ++i) {
    int node = node0 + w * 4 + i;
    int beg = be_[i].x, end = be_[i].y;
    float2v a01 = {0.f, 0.f}, a23 = {0.f, 0.f};

    {
      int cnt0 = min(64, end - beg);
      LADDER(sidx_[i], cnt0);
    }
#pragma unroll 1
    for (int e = beg + 64; e < end; e += 64) {   // rare: degree > 64
      int cnt = min(64, end - e);
      int sidx = (e + lane < end) ? csr[e + lane] : ZROW;
      LADDER(sidx, cnt);
    }

    // halves hold partial sums of the same 4 dims -> combine
    a01[0] += __shfl_xor(a01[0], 32, 64);
    a01[1] += __shfl_xor(a01[1], 32, 64);
    a23[0] += __shfl_xor(a23[0], 32, 64);
    a23[1] += __shfl_xor(a23[1], 32, 64);

    if (lane < 32) {
      // add own row (h = x + agg), write bf16 into hbuf (dims 4*lane..+3)
      unsigned sv = sv_[i];
      FADD2(sv);
      uint2 r;
      r.x = (unsigned)(unsigned short)f2bf(a01[0]) | ((unsigned)(unsigned short)f2bf(a01[1]) << 16);
      r.y = (unsigned)(unsigned short)f2bf(a23[0]) | ((unsigned)(unsigned short)f2bf(a23[1]) << 16);
      *(uint2*)&hbuf[(w * 4 + i) * LSTR + lane * 4] = r;
    }
  }
  __syncthreads();

  int q = lane >> 4, m = lane & 15;
  short8 a0f[4];
#pragma unroll
  for (int kk = 0; kk < 4; ++kk)
    a0f[kk] = *(short8*)&hbuf[m * LSTR + kk * 32 + q * 8];
  __syncthreads();

  f32x4 acc[2] = {};
#pragma unroll
  for (int kk = 0; kk < 4; ++kk)
#pragma unroll
    for (int j = 0; j < 2; ++j) {
      int nt = w * 2 + j;
      short8 bf = *(const short8*)&B1f[((nt * 4 + kk) * 64 + lane) * 8];
      acc[j] = __builtin_amdgcn_mfma_f32_16x16x32_bf16(a0f[kk], bf, acc[j], 0, 0, 0);
    }
#pragma unroll
  for (int j = 0; j < 2; ++j) {
    int nt = w * 2 + j;
    float bv = b1[nt * 16 + m];
#pragma unroll
    for (int r = 0; r < 4; ++r)
      hbuf[(q * 4 + r) * LSTR + nt * 16 + m] = f2bf(fmaxf(acc[j][r] + bv, 0.f));
  }
  __syncthreads();

  short8 a1f[4];
#pragma unroll
  for (int kk = 0; kk < 4; ++kk)
    a1f[kk] = *(short8*)&hbuf[m * LSTR + kk * 32 + q * 8];
  __syncthreads();

  f32x4 acc2v[2] = {};
#pragma unroll
  for (int kk = 0; kk < 4; ++kk)
#pragma unroll
    for (int j = 0; j < 2; ++j) {
      int nt = w * 2 + j;
      short8 bf = *(const short8*)&B2f[((nt * 4 + kk) * 64 + lane) * 8];
      acc2v[j] = __builtin_amdgcn_mfma_f32_16x16x32_bf16(a1f[kk], bf, acc2v[j], 0, 0, 0);
    }
#pragma unroll
  for (int j = 0; j < 2; ++j) {
    int nt = w * 2 + j;
    float bv = b2[nt * 16 + m];
#pragma unroll
    for (int r = 0; r < 4; ++r)
      hbuf[(q * 4 + r) * LSTR + nt * 16 + m] = f2bf(acc2v[j][r] + bv);
  }
  __syncthreads();

  {
    int row = t >> 4, c8 = t & 15;
    short8 vv = *(short8*)&hbuf[row * LSTR + c8 * 8];
    int node = node0 + row;
    if (xf8out) {
      float f0 = bfu((unsigned short)vv[0]), f1 = bfu((unsigned short)vv[1]);
      float f2 = bfu((unsigned short)vv[2]), f3 = bfu((unsigned short)vv[3]);
      float f4 = bfu((unsigned short)vv[4]), f5 = bfu((unsigned short)vv[5]);
      float f6 = bfu((unsigned short)vv[6]), f7 = bfu((unsigned short)vv[7]);
      uint2 r;
      r.x = pk_fp8x4(f0, f1, f2, f3);
      r.y = pk_fp8x4(f4, f5, f6, f7);
      *(uint2*)&xf8out[((size_t)node << 7) + c8 * 8] = r;
    }
    if (xbfout)
      *(short8*)&xbfout[(size_t)node * D + c8 * 8] = vv;
  }
}

// ---------------- tvec: 128-block column-parallel GEMV (kept from v13) ----------------

__global__ __launch_bounds__(256) void tvec_kernel(const unsigned short* __restrict__ x,
                                                   const int* __restrict__ ep,
                                                   const float* __restrict__ W1,
                                                   const float* __restrict__ b1,
                                                   float* __restrict__ tvec) {
  __shared__ float red[4];
  int j = blockIdx.x;        // output column 0..127
  int t = threadIdx.x;       // k = t in 0..255
  int w = t >> 6, lane = t & 63;
  int u = ep[0], v = ep[1];
  int seg = t >> 7, kk = t & 127;
  float xu = bfu(x[(size_t)u * D + kk]);
  float xv = bfu(x[(size_t)v * D + kk]);
  float f = seg ? fabsf(xu - xv) : (xu + xv);
  float p = f * W1[t * D + j];
#pragma unroll
  for (int m = 1; m < 64; m <<= 1) p += __shfl_xor(p, m, 64);
  if (lane == 0) red[w] = p;
  __syncthreads();
  if (t == 0) tvec[j] = b1[j] + red[0] + red[1] + red[2] + red[3];
}

// ---------------- predictor (round-13 bf16 staging, known-good): 64 cands/block,
// swizzled staging, tvec from global ----------------

__global__ __launch_bounds__(256) void pred_kernel(const unsigned short* __restrict__ x,
                                                   const int* __restrict__ cand,
                                                   const short* __restrict__ Wf,
                                                   const float* __restrict__ tvec,
                                                   const float* __restrict__ w2,
                                                   const float* __restrict__ b2,
                                                   float* __restrict__ out) {
  __shared__ short sS[8192];   // 16 KB
  __shared__ short sD[8192];   // 16 KB
  int t = threadIdx.x;
  int blockRow = blockIdx.x * 64;
  int w = t >> 6, lane = t & 63;

  short8 U[4], V[4];
#pragma unroll
  for (int i = 0; i < 4; ++i) {
    int idx = t + i * 256;
    int c = blockRow + (idx >> 4);
    int2 uv = ((const int2*)cand)[c];
    int j8 = idx & 15;
    U[i] = *(const short8*)&x[(size_t)uv.x * D + j8 * 8];
    V[i] = *(const short8*)&x[(size_t)uv.y * D + j8 * 8];
  }
#pragma unroll
  for (int i = 0; i < 4; ++i) {
    int idx = t + i * 256;
    int m = idx >> 4, j8 = idx & 15;
    short8 ss, sd;
#pragma unroll
    for (int j = 0; j < 8; ++j) {
      float uf = bfu((unsigned short)U[i][j]);
      float vf = bfu((unsigned short)V[i][j]);
      ss[j] = f2bf(uf + vf);
      sd[j] = f2bf(fabsf(uf - vf));
    }
    int kk = j8 >> 2, qq = j8 & 3, mt = m >> 4, ln = (m & 15) | (qq << 4);
    int byte = ((mt * 4 + kk) * 64 + ln) * 16;
    byte = swz(byte);
    *(short8*)((char*)sS + byte) = ss;
    *(short8*)((char*)sD + byte) = sd;
  }
  __syncthreads();

  f32x4 acc[8] = {};
  const short* B0 = Wf + 6 * 16384;
  const short* B1 = Wf + 7 * 16384;
  for (int kk = 0; kk < 4; ++kk) {
    int byteA = swz(((w * 4 + kk) * 64 + lane) * 16);
    short8 a0 = *(short8*)((char*)sS + byteA);
    short8 a1 = *(short8*)((char*)sD + byteA);
#pragma unroll
    for (int nt = 0; nt < 8; ++nt) {
      short8 b0 = *(const short8*)&B0[((nt * 4 + kk) * 64 + lane) * 8];
      short8 b1f = *(const short8*)&B1[((nt * 4 + kk) * 64 + lane) * 8];
      acc[nt] = __builtin_amdgcn_mfma_f32_16x16x32_bf16(a0, b0, acc[nt], 0, 0, 0);
      acc[nt] = __builtin_amdgcn_mfma_f32_16x16x32_bf16(a1, b1f, acc[nt], 0, 0, 0);
    }
  }

  int colbase = lane & 15, rq = lane >> 4;
  float tv[8], w2v[8];
#pragma unroll
  for (int nt = 0; nt < 8; ++nt) {
    tv[nt] = tvec[nt * 16 + colbase];
    w2v[nt] = w2[nt * 16 + colbase];
  }
  float b2v = b2[0];
  {
    float part[4] = {0.f, 0.f, 0.f, 0.f};
#pragma unroll
    for (int nt = 0; nt < 8; ++nt)
#pragma unroll
      for (int r = 0; r < 4; ++r) {
        float h = acc[nt][r] + tv[nt];
        h = fmaxf(h, 0.f);
        part[r] += h * w2v[nt];
      }
#pragma unroll
    for (int r = 0; r < 4; ++r)
      for (int msk = 1; msk < 16; msk <<= 1)
        part[r] += __shfl_xor(part[r], msk, 64);
    if (colbase == 0) {
      int row0 = blockRow + w * 16 + rq * 4;
#pragma unroll
      for (int r = 0; r < 4; ++r) out[row0 + r] = part[r] + b2v;
    }
  }
}

// ---------------- launch ----------------

extern "C" void kernel_launch(void* const* d_in, const int* in_sizes, int n_in,
                              void* d_out, int out_size, void* d_ws, size_t ws_size,
                              hipStream_t stream) {
  const float* x_in = (const float*)d_in[0];
  const int* edge_index = (const int*)d_in[1];
  const int* ep = (const int*)d_in[2];
  const int* cand = (const int*)d_in[3];
  const float* gw1 = (const float*)d_in[4];
  const float* gb1 = (const float*)d_in[5];
  const float* gw2 = (const float*)d_in[6];
  const float* gb2 = (const float*)d_in[7];
  const float* pw1 = (const float*)d_in[8];
  const float* pb1 = (const float*)d_in[9];
  const float* pw2 = (const float*)d_in[10];
  const float* pb2 = (const float*)d_in[11];
  float* out = (float*)d_out;

  char* ws = (char*)d_ws;
  size_t off = 0;
  auto alloc = [&](size_t bytes) {
    void* p = ws + off;
    off += (bytes + 255) & ~(size_t)255;
    return p;
  };
  unsigned char* xf8A = (unsigned char*)alloc((size_t)ROWS * 128);  // fp8 row-major
  unsigned char* xf8B = (unsigned char*)alloc((size_t)ROWS * 128);
  unsigned short* xbf = (unsigned short*)alloc((size_t)ROWS * D * 2);  // bf16 (layer-3 out)
  int* pairs       = (int*)alloc((size_t)NB * BCAP * 4);
  int* csr         = (int*)alloc((size_t)NB * BCAP * 4);
  int2* rowBE      = (int2*)alloc((size_t)N_NODES * 8);
  int* bucket_cnt  = (int*)alloc((size_t)NB * 4);
  short* Wf        = (short*)alloc((size_t)8 * 16384 * 2);
  float* tvec      = (float*)alloc((size_t)D * 4);

  const int* src = edge_index;
  const int* dst = edge_index + N_EDGES;

  (void)hipMemsetAsync(bucket_cnt, 0, (size_t)NB * 4, stream);

  prep_pass1<<<3581, 256, 0, stream>>>(gw1, gw2, pw1, Wf, x_in, xf8A, xf8B,
                                       src, dst, bucket_cnt, pairs);
  build_pass2<<<NB, 512, 0, stream>>>(pairs, bucket_cnt, rowBE, csr);

  const int gin_grid = N_NODES / 16;  // 3125
  gin_layer<<<gin_grid, 256, 0, stream>>>(xf8A, rowBE, csr, Wf + 0 * 16384, gb1 + 0 * D,
                                          Wf + 3 * 16384, gb2 + 0 * D, xf8B, nullptr);
  gin_layer<<<gin_grid, 256, 0, stream>>>(xf8B, rowBE, csr, Wf + 1 * 16384, gb1 + 1 * D,
                                          Wf + 4 * 16384, gb2 + 1 * D, xf8A, nullptr);
  gin_layer<<<gin_grid, 256, 0, stream>>>(xf8A, rowBE, csr, Wf + 2 * 16384, gb1 + 2 * D,
                                          Wf + 5 * 16384, gb2 + 2 * D, nullptr, xbf);

  tvec_kernel<<<D, 256, 0, stream>>>(xbf, ep, pw1, pb1, tvec);
  pred_kernel<<<N_CAND / 64, 256, 0, stream>>>(xbf, cand, Wf, tvec, pw2, pb2, out);
}